// Round 1
// baseline (6220.346 us; speedup 1.0000x reference)
//
#include <hip/hip_runtime.h>
#include <math.h>

#define MAX_DELAY 128
#define INPUT 64
#define HIDDEN 128
#define HALF 64
#define OUT 64
#define BATCH 32
#define T 128
#define OUT_LEN 64

// One block per batch element (the 32 sequences are independent; each is a
// strictly sequential recurrence of up to T+OUT_LEN steps). 128 threads:
// thread h owns hidden channel h. The delay buffer row buf[h][0..127] lives
// fully in registers (unrolled float[128]); the per-step "shift" is register
// moves, the blend is pure VALU. Cross-channel vectors (buf[:,0], msg, h1)
// are exchanged through small LDS arrays.
__global__ __launch_bounds__(128, 1) void delayrnn_kernel(
    const float* __restrict__ x,        // (B, T, INPUT)
    const int*   __restrict__ lengths,  // (B)
    const float* __restrict__ Wm,       // (INPUT+HIDDEN, HIDDEN) row-major
    const float* __restrict__ bm,       // (HIDDEN)
    const float* __restrict__ W1,       // (HIDDEN, HALF)
    const float* __restrict__ b1,       // (HALF)
    const float* __restrict__ W2,       // (HALF, 2*HIDDEN)
    const float* __restrict__ b2,       // (2*HIDDEN)
    const float* __restrict__ Wo,       // (HIDDEN, OUT)
    const float* __restrict__ bo,       // (OUT)
    float* __restrict__ out)            // (B, OUT_LEN, OUT)
{
    const int b = blockIdx.x;
    const int h = threadIdx.x;          // 0..127
    const int len = lengths[b];         // in [0, T)

    // Delay buffer row for channel h, logical index d (0 = front).
    float buf[MAX_DELAY];
#pragma unroll
    for (int d = 0; d < MAX_DELAY; ++d) buf[d] = 0.0f;

    __shared__ float s_buf0[HIDDEN];
    __shared__ float s_msg[HIDDEN];
    __shared__ float s_h1[HALF];

    const float tau_h = 0.0f; (void)tau_h;

    // -------- encoder: only the first `len` steps touch the buffer --------
    for (int t = 0; t < len; ++t) {
        const float* xt = x + (b * T + t) * INPUT;

        s_buf0[h] = buf[0];
        __syncthreads();

        // msg[h] = tanh( [x_t, buf0] . Wm[:,h] + bm[h] )
        float acc = bm[h];
        for (int i = 0; i < INPUT; ++i)
            acc = fmaf(xt[i], Wm[i * HIDDEN + h], acc);
        for (int j = 0; j < HIDDEN; ++j)
            acc = fmaf(s_buf0[j], Wm[(INPUT + j) * HIDDEN + h], acc);
        float msg = tanhf(acc);
        s_msg[h] = msg;
        __syncthreads();

        // h1[k] = relu(msg . W1[:,k] + b1[k]), k < 64
        if (h < HALF) {
            float a1 = b1[h];
            for (int j = 0; j < HIDDEN; ++j)
                a1 = fmaf(s_msg[j], W1[j * HALF + h], a1);
            s_h1[h] = fmaxf(a1, 0.0f);
        }
        __syncthreads();

        // tau[h] = sigmoid(h1 . W2[:,h] + b2[h]); mem_i[h] = column h+128
        float at = b2[h];
        float am = b2[HIDDEN + h];
        for (int k = 0; k < HALF; ++k) {
            float hk = s_h1[k];
            at = fmaf(hk, W2[k * (2 * HIDDEN) + h], at);
            am = fmaf(hk, W2[k * (2 * HIDDEN) + HIDDEN + h], am);
        }
        float tau = 1.0f / (1.0f + expf(-at));
        float mem = 1.0f / (1.0f + expf(-am));

        // buffer update: shift left, blend with msg by iw
#pragma unroll
        for (int d = 0; d < MAX_DELAY; ++d) {
            float nb = (d < MAX_DELAY - 1) ? buf[d + 1] : 0.0f;
            float w = 1.0f - fabsf(tau - (float)d * (1.0f / MAX_DELAY));
            float iw = mem * w * w;
            buf[d] = nb + iw * (msg - nb);   // (1-iw)*nb + iw*msg
        }
        __syncthreads();   // protect s_buf0/s_msg/s_h1 before next step
    }

    // -------- decoder: 64 unmasked steps, x0 = 0 --------
    for (int t = 0; t < OUT_LEN; ++t) {
        s_buf0[h] = buf[0];
        __syncthreads();

        // msg[h] = tanh( buf0 . Wm[64:,h] + bm[h] )   (x0 contributes 0)
        float acc = bm[h];
        for (int j = 0; j < HIDDEN; ++j)
            acc = fmaf(s_buf0[j], Wm[(INPUT + j) * HIDDEN + h], acc);
        float msg = tanhf(acc);
        s_msg[h] = msg;
        __syncthreads();

        if (h < HALF) {
            float a1 = b1[h];
            for (int j = 0; j < HIDDEN; ++j)
                a1 = fmaf(s_msg[j], W1[j * HALF + h], a1);
            s_h1[h] = fmaxf(a1, 0.0f);
        }
        __syncthreads();

        float at = b2[h];
        float am = b2[HIDDEN + h];
        for (int k = 0; k < HALF; ++k) {
            float hk = s_h1[k];
            at = fmaf(hk, W2[k * (2 * HIDDEN) + h], at);
            am = fmaf(hk, W2[k * (2 * HIDDEN) + HIDDEN + h], am);
        }
        float tau = 1.0f / (1.0f + expf(-at));
        float mem = 1.0f / (1.0f + expf(-am));

#pragma unroll
        for (int d = 0; d < MAX_DELAY; ++d) {
            float nb = (d < MAX_DELAY - 1) ? buf[d + 1] : 0.0f;
            float w = 1.0f - fabsf(tau - (float)d * (1.0f / MAX_DELAY));
            float iw = mem * w * w;
            buf[d] = nb + iw * (msg - nb);
        }

        // out[b, t, :] = msg . Wo + bo
        if (h < OUT) {
            float ao = bo[h];
            for (int j = 0; j < HIDDEN; ++j)
                ao = fmaf(s_msg[j], Wo[j * OUT + h], ao);
            out[(b * OUT_LEN + t) * OUT + h] = ao;
        }
        __syncthreads();
    }
}

extern "C" void kernel_launch(void* const* d_in, const int* in_sizes, int n_in,
                              void* d_out, int out_size, void* d_ws, size_t ws_size,
                              hipStream_t stream) {
    const float* x       = (const float*)d_in[0];
    const int*   lengths = (const int*)  d_in[1];
    // d_in[2] = out_lengths scalar (fixed 64, compile-time)
    const float* Wm = (const float*)d_in[3];
    const float* bm = (const float*)d_in[4];
    const float* W1 = (const float*)d_in[5];
    const float* b1 = (const float*)d_in[6];
    const float* W2 = (const float*)d_in[7];
    const float* b2 = (const float*)d_in[8];
    const float* Wo = (const float*)d_in[9];
    const float* bo = (const float*)d_in[10];
    float* out = (float*)d_out;

    delayrnn_kernel<<<BATCH, 128, 0, stream>>>(
        x, lengths, Wm, bm, W1, b1, W2, b2, Wo, bo, out);
}

// Round 2
// 408.700 us; speedup vs baseline: 15.2198x; 15.2198x over previous
//
#include <hip/hip_runtime.h>
#include <math.h>

#define MAX_DELAY 128
#define INPUT 64
#define HIDDEN 128
#define HALF 64
#define OUT 64
#define BATCH 32
#define T 128
#define OUT_LEN 64
#define NTHR 512

// One block (512 threads = 8 waves) per batch element. ALL weights live in
// registers, distributed across threads; activations are exchanged via small
// LDS arrays; dot-product partials reduce via intra-wave __shfl_xor.
//
// Register budget/thread: 48 (Wm col slice) + 16 (W1) + 32 (W2) + 16 (Wo)
// + 32 (buffer: channel h = tid>>2, delays q*32..q*32+31) ≈ 144 array regs
// + scalars -> ~180 VGPR, fits __launch_bounds__(512,2) (256 VGPR cap).
__global__ __launch_bounds__(NTHR, 2) void delayrnn_kernel(
    const float* __restrict__ x,        // (B, T, INPUT)
    const int*   __restrict__ lengths,  // (B)
    const float* __restrict__ Wm,       // (INPUT+HIDDEN, HIDDEN)
    const float* __restrict__ bm,       // (HIDDEN)
    const float* __restrict__ W1,       // (HIDDEN, HALF)
    const float* __restrict__ b1,       // (HALF)
    const float* __restrict__ W2,       // (HALF, 2*HIDDEN)
    const float* __restrict__ b2,       // (2*HIDDEN)
    const float* __restrict__ Wo,       // (HIDDEN, OUT)
    const float* __restrict__ bo,       // (OUT)
    float* __restrict__ out)            // (B, OUT_LEN, OUT)
{
    const int b   = blockIdx.x;
    const int tid = threadIdx.x;
    const int len = lengths[b];

    // role mappings (all intra-wave groups for the shuffles)
    const int h  = tid >> 2;  const int q  = tid & 3;  // msg / buffer
    const int k1 = tid >> 3;  const int r1 = tid & 7;  // h1 (64 outs, 8 thr each)
    const int c2 = tid >> 1;  const int r2 = tid & 1;  // tau/mem (256 outs, 2 thr)
    const int co = tid >> 3;  const int ro = tid & 7;  // out (64 outs, 8 thr)

    // ---- one-time: weights -> registers ----
    float wm_reg[48];
#pragma unroll
    for (int i = 0; i < 48; ++i) wm_reg[i] = Wm[(q * 48 + i) * HIDDEN + h];
    float w1_reg[16];
#pragma unroll
    for (int j = 0; j < 16; ++j) w1_reg[j] = W1[(r1 * 16 + j) * HALF + k1];
    float w2_reg[32];
#pragma unroll
    for (int j = 0; j < 32; ++j) w2_reg[j] = W2[(r2 * 32 + j) * (2 * HIDDEN) + c2];
    float wo_reg[16];
#pragma unroll
    for (int j = 0; j < 16; ++j) wo_reg[j] = Wo[(ro * 16 + j) * OUT + co];
    const float bm_r = bm[h];
    const float b1_r = b1[k1];
    const float b2_r = b2[c2];
    const float bo_r = bo[co];

    // buffer slice: channel h, global delays q*32 .. q*32+31
    float buf[32];
#pragma unroll
    for (int d = 0; d < 32; ++d) buf[d] = 0.f;

    __shared__ float s_x[T * INPUT];            // staged input row-block (32 KB)
    __shared__ float s_v[INPUT + HIDDEN];       // [x_t | buf0]
    __shared__ float s_msg[HIDDEN];
    __shared__ float s_h1[HALF];
    __shared__ float s_tau[HIDDEN];
    __shared__ float s_mem[HIDDEN];
    __shared__ float s_head[2][NTHR];           // double-buffered shift exchange

    for (int idx = tid; idx < T * INPUT; idx += NTHR)
        s_x[idx] = x[b * T * INPUT + idx];
    __syncthreads();

    const int total = len + OUT_LEN;
    int par = 0;

    for (int step = 0; step < total; ++step) {
        const bool dec = (step >= len);         // uniform across block

        // ---- phase A: publish heads + assemble v = [x_t | buf0] ----
        s_head[par][tid] = buf[0];
        if (q == 0) s_v[INPUT + h] = buf[0];
        if (tid < INPUT) s_v[tid] = dec ? 0.f : s_x[step * INPUT + tid];
        __syncthreads();

        // ---- msg[h] = tanh(v . Wm[:,h] + bm[h]) ----
        float p = 0.f;
#pragma unroll
        for (int i = 0; i < 48; ++i) p = fmaf(wm_reg[i], s_v[q * 48 + i], p);
        p += __shfl_xor(p, 1, 64);
        p += __shfl_xor(p, 2, 64);
        const float zt = p + bm_r;
        const float ez = __expf(-2.f * zt);
        const float msg = (1.f - ez) / (1.f + ez);   // tanh
        if (q == 0) s_msg[h] = msg;
        __syncthreads();

        // ---- h1[k] = relu(msg . W1[:,k] + b1[k]) ----
        float p1 = 0.f;
#pragma unroll
        for (int j = 0; j < 16; ++j) p1 = fmaf(w1_reg[j], s_msg[r1 * 16 + j], p1);
        p1 += __shfl_xor(p1, 1, 64);
        p1 += __shfl_xor(p1, 2, 64);
        p1 += __shfl_xor(p1, 4, 64);
        if (r1 == 0) s_h1[k1] = fmaxf(p1 + b1_r, 0.f);
        __syncthreads();

        // ---- tau/mem = sigmoid(h1 . W2 + b2) ----
        float p2 = 0.f;
#pragma unroll
        for (int j = 0; j < 32; ++j) p2 = fmaf(w2_reg[j], s_h1[r2 * 32 + j], p2);
        p2 += __shfl_xor(p2, 1, 64);
        const float g = 1.f / (1.f + __expf(-(p2 + b2_r)));
        if (r2 == 0) { if (c2 < HIDDEN) s_tau[c2] = g; else s_mem[c2 - HIDDEN] = g; }
        __syncthreads();

        // ---- buffer shift + blend (channel h, delays q*32+d) ----
        {
            const float tau = s_tau[h];
            const float mem = s_mem[h];
            const float m   = s_msg[h];
            const float head_next = (q < 3) ? s_head[par][tid + 1] : 0.f;
#pragma unroll
            for (int d = 0; d < 32; ++d) {
                const float nb = (d < 31) ? buf[d + 1] : head_next;
                const float iv = (float)(q * 32 + d) * (1.0f / MAX_DELAY);
                const float w  = 1.f - fabsf(tau - iv);
                const float iw = mem * w * w;
                buf[d] = nb + iw * (m - nb);        // (1-iw)*nb + iw*msg
            }
        }

        // ---- decode output: out = msg . Wo + bo ----
        if (dec) {
            float po = 0.f;
#pragma unroll
            for (int j = 0; j < 16; ++j) po = fmaf(wo_reg[j], s_msg[ro * 16 + j], po);
            po += __shfl_xor(po, 1, 64);
            po += __shfl_xor(po, 2, 64);
            po += __shfl_xor(po, 4, 64);
            if (ro == 0) out[(b * OUT_LEN + (step - len)) * OUT + co] = po + bo_r;
        }
        par ^= 1;
        // no end barrier: s_head is double-buffered; all other shared arrays
        // are rewritten only after at least one barrier separates the writers
        // from this step's readers.
    }
}

extern "C" void kernel_launch(void* const* d_in, const int* in_sizes, int n_in,
                              void* d_out, int out_size, void* d_ws, size_t ws_size,
                              hipStream_t stream) {
    const float* x       = (const float*)d_in[0];
    const int*   lengths = (const int*)  d_in[1];
    // d_in[2] = out_lengths scalar (compile-time 64)
    const float* Wm = (const float*)d_in[3];
    const float* bm = (const float*)d_in[4];
    const float* W1 = (const float*)d_in[5];
    const float* b1 = (const float*)d_in[6];
    const float* W2 = (const float*)d_in[7];
    const float* b2 = (const float*)d_in[8];
    const float* Wo = (const float*)d_in[9];
    const float* bo = (const float*)d_in[10];
    float* out = (float*)d_out;

    delayrnn_kernel<<<BATCH, NTHR, 0, stream>>>(
        x, lengths, Wm, bm, W1, b1, W2, b2, Wo, bo, out);
}

// Round 3
// 375.275 us; speedup vs baseline: 16.5755x; 1.0891x over previous
//
#include <hip/hip_runtime.h>
#include <math.h>

typedef __attribute__((ext_vector_type(2))) float f32x2;

#define MAX_DELAY 128
#define INPUT 64
#define HIDDEN 128
#define HALF 64
#define OUT 64
#define BATCH 32
#define T 128
#define OUT_LEN 64
#define NTHR 512

static __device__ __forceinline__ f32x2 splat2(float v) { f32x2 r; r.x = v; r.y = v; return r; }

// One block (512 thr / 8 waves) per batch. Weights register-resident.
// 3 barriers per step (v, msg, h1 broadcasts); tau/mem are computed
// wave-locally (wave w produces channels [16w,16w+16)) and exchanged via a
// wave-private LDS strip with no block barrier. All matvecs + the blend use
// packed fp32 (v_pk_fma_f32) via ext_vector float2.
__global__ __launch_bounds__(NTHR) __attribute__((amdgpu_waves_per_eu(2, 2)))
void delayrnn_kernel(
    const float* __restrict__ x,        // (B, T, INPUT)
    const int*   __restrict__ lengths,  // (B)
    const float* __restrict__ Wm,       // (INPUT+HIDDEN, HIDDEN)
    const float* __restrict__ bm,       // (HIDDEN)
    const float* __restrict__ W1,       // (HIDDEN, HALF)
    const float* __restrict__ b1,       // (HALF)
    const float* __restrict__ W2,       // (HALF, 2*HIDDEN)
    const float* __restrict__ b2,       // (2*HIDDEN)
    const float* __restrict__ Wo,       // (HIDDEN, OUT)
    const float* __restrict__ bo,       // (OUT)
    float* __restrict__ out)            // (B, OUT_LEN, OUT)
{
    const int b   = blockIdx.x;
    const int tid = threadIdx.x;
    const int len = lengths[b];

    // role mappings
    const int h  = tid >> 2;  const int q  = tid & 3;   // msg / buffer channel
    const int k1 = tid >> 3;  const int r1 = tid & 7;   // h1
    const int wv = tid >> 6;  const int ln = tid & 63;  // wave / lane
    const int o2 = ln >> 1;   const int r2 = ln & 1;    // tau-mem (wave-local)
    const int col2 = wv * 16 + (o2 & 15) + (o2 >> 4) * 128; // W2 column
    const int co = tid >> 3;  const int ro = tid & 7;   // out proj

    // ---- weights -> registers (packed pairs along the k dimension) ----
    f32x2 wm2[24];
#pragma unroll
    for (int i = 0; i < 24; ++i) {
        wm2[i].x = Wm[(q * 48 + 2 * i)     * HIDDEN + h];
        wm2[i].y = Wm[(q * 48 + 2 * i + 1) * HIDDEN + h];
    }
    f32x2 w12[8];
#pragma unroll
    for (int j = 0; j < 8; ++j) {
        w12[j].x = W1[(r1 * 16 + 2 * j)     * HALF + k1];
        w12[j].y = W1[(r1 * 16 + 2 * j + 1) * HALF + k1];
    }
    f32x2 w22[16];
#pragma unroll
    for (int j = 0; j < 16; ++j) {
        w22[j].x = W2[(r2 * 32 + 2 * j)     * (2 * HIDDEN) + col2];
        w22[j].y = W2[(r2 * 32 + 2 * j + 1) * (2 * HIDDEN) + col2];
    }
    f32x2 wo2[8];
#pragma unroll
    for (int j = 0; j < 8; ++j) {
        wo2[j].x = Wo[(ro * 16 + 2 * j)     * OUT + co];
        wo2[j].y = Wo[(ro * 16 + 2 * j + 1) * OUT + co];
    }
    const float bm_r = bm[h];
    const float b1_r = b1[k1];
    const float b2_r = b2[col2];
    const float bo_r = bo[co];

    // buffer slice: channel h, delays q*32 .. q*32+31
    float buf[32];
#pragma unroll
    for (int d = 0; d < 32; ++d) buf[d] = 0.f;

    __shared__ float s_x[T * INPUT];       // 32 KB staged input
    __shared__ float s_v[INPUT + HIDDEN];  // [x_t | buf0]
    __shared__ float s_msg[HIDDEN];
    __shared__ float s_h1[HALF];
    __shared__ float s_tm[8][32];          // wave-private tau|mem strips
    __shared__ float s_head[2][NTHR];      // double-buffered shift exchange

    for (int idx = tid; idx < T * INPUT; idx += NTHR)
        s_x[idx] = x[b * T * INPUT + idx];
    __syncthreads();

    int par = 0;
    const float base_iv = (float)q * 0.25f;   // (q*32)/128

#define STEP_BODY(IS_DEC, TPOS)                                               \
    {                                                                         \
        /* publish heads + v */                                               \
        s_head[par][tid] = buf[0];                                            \
        if (q == 0) s_v[INPUT + h] = buf[0];                                  \
        if (!(IS_DEC) && tid < INPUT) s_v[tid] = s_x[(TPOS) * INPUT + tid];   \
        __syncthreads();  /* B1 */                                            \
        /* msg = tanh(v . Wm + bm) */                                         \
        const f32x2* v2 = (const f32x2*)(s_v + q * 48);                       \
        f32x2 am2 = splat2(0.f);                                              \
        _Pragma("unroll")                                                     \
        for (int i = 0; i < 24; ++i) am2 += wm2[i] * v2[i];                   \
        float p = am2.x + am2.y;                                              \
        p += __shfl_xor(p, 1, 64);                                            \
        p += __shfl_xor(p, 2, 64);                                            \
        const float zt = p + bm_r;                                            \
        const float ez = __expf(-2.f * zt);                                   \
        const float msg = (1.f - ez) / (1.f + ez);                            \
        if (q == 0) s_msg[h] = msg;                                           \
        __syncthreads();  /* B2 */                                            \
        /* h1 = relu(msg . W1 + b1) */                                        \
        const f32x2* m2 = (const f32x2*)(s_msg + r1 * 16);                    \
        f32x2 a12 = splat2(0.f);                                              \
        _Pragma("unroll")                                                     \
        for (int j = 0; j < 8; ++j) a12 += w12[j] * m2[j];                    \
        float p1 = a12.x + a12.y;                                             \
        p1 += __shfl_xor(p1, 1, 64);                                          \
        p1 += __shfl_xor(p1, 2, 64);                                          \
        p1 += __shfl_xor(p1, 4, 64);                                          \
        if (r1 == 0) s_h1[k1] = fmaxf(p1 + b1_r, 0.f);                        \
        __syncthreads();  /* B3 */                                            \
        /* tau/mem: wave-local (wave wv covers its own blend channels) */     \
        const f32x2* h2 = (const f32x2*)(s_h1 + r2 * 32);                     \
        f32x2 a22 = splat2(0.f);                                              \
        _Pragma("unroll")                                                     \
        for (int j = 0; j < 16; ++j) a22 += w22[j] * h2[j];                   \
        float p2 = a22.x + a22.y;                                             \
        p2 += __shfl_xor(p2, 1, 64);                                          \
        const float g = 1.f / (1.f + __expf(-(p2 + b2_r)));                   \
        if (r2 == 0) s_tm[wv][o2] = g;                                        \
        /* blend (reads wave-private s_tm: in-order within wave, no barrier) */\
        {                                                                     \
            const f32x2 tau2 = splat2(s_tm[wv][h & 15]);                      \
            const f32x2 mem2 = splat2(s_tm[wv][16 + (h & 15)]);               \
            const f32x2 msg2 = splat2(s_msg[h]);                              \
            const float head_next = (q < 3) ? s_head[par][tid + 1] : 0.f;     \
            const f32x2 one2 = splat2(1.f);                                   \
            _Pragma("unroll")                                                 \
            for (int mm = 0; mm < 16; ++mm) {                                 \
                const int d = 2 * mm;                                         \
                f32x2 nb;                                                     \
                nb.x = buf[d + 1];                                            \
                nb.y = (mm < 15) ? buf[d + 2] : head_next;                    \
                f32x2 iv;                                                     \
                iv.x = base_iv + (float)d       * (1.f / MAX_DELAY);          \
                iv.y = base_iv + (float)(d + 1) * (1.f / MAX_DELAY);          \
                f32x2 u = iv - tau2;                                          \
                f32x2 a = __builtin_elementwise_max(u, -u);                   \
                f32x2 w = one2 - a;                                           \
                f32x2 iw = mem2 * w * w;                                      \
                f32x2 dl = msg2 - nb;                                         \
                f32x2 nv = iw * dl + nb;                                      \
                buf[d] = nv.x; buf[d + 1] = nv.y;                             \
            }                                                                 \
        }                                                                     \
        /* decode projection */                                               \
        if (IS_DEC) {                                                         \
            const f32x2* mo2 = (const f32x2*)(s_msg + ro * 16);               \
            f32x2 ao2 = splat2(0.f);                                          \
            _Pragma("unroll")                                                 \
            for (int j = 0; j < 8; ++j) ao2 += wo2[j] * mo2[j];               \
            float po = ao2.x + ao2.y;                                         \
            po += __shfl_xor(po, 1, 64);                                      \
            po += __shfl_xor(po, 2, 64);                                      \
            po += __shfl_xor(po, 4, 64);                                      \
            if (ro == 0) out[(b * OUT_LEN + (TPOS)) * OUT + co] = po + bo_r;  \
        }                                                                     \
        par ^= 1;                                                             \
    }

    // -------- encoder (masked steps beyond len are exact no-ops: skip) -----
    for (int t = 0; t < len; ++t) STEP_BODY(false, t)

    // x part of v is zero for all decode steps; write once.
    if (tid < INPUT) s_v[tid] = 0.f;   // made visible by first decode B1

    // -------- decoder --------
    for (int t = 0; t < OUT_LEN; ++t) STEP_BODY(true, t)

#undef STEP_BODY
}

extern "C" void kernel_launch(void* const* d_in, const int* in_sizes, int n_in,
                              void* d_out, int out_size, void* d_ws, size_t ws_size,
                              hipStream_t stream) {
    const float* x       = (const float*)d_in[0];
    const int*   lengths = (const int*)  d_in[1];
    // d_in[2] = out_lengths scalar (compile-time 64)
    const float* Wm = (const float*)d_in[3];
    const float* bm = (const float*)d_in[4];
    const float* W1 = (const float*)d_in[5];
    const float* b1 = (const float*)d_in[6];
    const float* W2 = (const float*)d_in[7];
    const float* b2 = (const float*)d_in[8];
    const float* Wo = (const float*)d_in[9];
    const float* bo = (const float*)d_in[10];
    float* out = (float*)d_out;

    delayrnn_kernel<<<BATCH, NTHR, 0, stream>>>(
        x, lengths, Wm, bm, W1, b1, W2, b2, Wo, bo, out);
}